// Round 8
// baseline (694.570 us; speedup 1.0000x reference)
//
#include <hip/hip_runtime.h>
#include <math.h>

#define D_ 128
#define H_ 160
#define W_ 160
#define HW_ (H_ * W_)            // 25600
#define V_ (D_ * H_ * W_)        // 3,276,800
#define SMOOTHF 1e-5

#define R_ 16                    // rows covered per block (TY + 6 halo)
#define TY 10                    // output rows per block
#define ZC 16                    // z-planes produced per block
#define COLS 40                  // float4 columns (W_/4)
#define NT 640                   // R_ * COLS threads (10 waves)
#define LROW 41                  // padded row length in float4 (164 floats)
#define NYT 16                   // H_/TY
#define NZC 8                    // D_/ZC
#define NTB (NYT * NZC)          // 128 tiles per volume

__device__ __forceinline__ float max3f(float a, float b, float c) { return fmaxf(fmaxf(a, b), c); }
__device__ __forceinline__ float min3f(float a, float b, float c) { return fminf(fminf(a, b), c); }
__device__ __forceinline__ float4 f4min(float4 a, float4 b) {
    return make_float4(fminf(a.x,b.x), fminf(a.y,b.y), fminf(a.z,b.z), fminf(a.w,b.w));
}
__device__ __forceinline__ float4 f4max(float4 a, float4 b) {
    return make_float4(fmaxf(a.x,b.x), fmaxf(a.y,b.y), fmaxf(a.z,b.z), fmaxf(a.w,b.w));
}
// sliding 3-window min/max along x of (l | c | r)
__device__ __forceinline__ float4 min3x(float l, float4 c, float r) {
    return make_float4(min3f(l,c.x,c.y), min3f(c.x,c.y,c.z), min3f(c.y,c.z,c.w), min3f(c.z,c.w,r));
}
__device__ __forceinline__ float4 max3x(float l, float4 c, float r) {
    return make_float4(max3f(l,c.x,c.y), max3f(c.x,c.y,c.z), max3f(c.y,c.z,c.w), max3f(c.z,c.w,r));
}
__device__ __forceinline__ float4 relu4sub(float4 a, float4 b) {   // relu(a-b)
    return make_float4(fmaxf(a.x-b.x,0.f), fmaxf(a.y-b.y,0.f), fmaxf(a.z-b.z,0.f), fmaxf(a.w-b.w,0.f));
}
__device__ __forceinline__ float4 skel_upd(float4 s, float4 d) {   // s + relu(d - s*d)
    return make_float4(s.x + fmaxf(d.x - s.x*d.x, 0.f), s.y + fmaxf(d.y - s.y*d.y, 0.f),
                       s.z + fmaxf(d.z - s.z*d.z, 0.f), s.w + fmaxf(d.w - s.w*d.w, 0.f));
}

// vol i in 0..7: 0..3 = pred (b=i>>1, ch=(i&1)+1), 4..7 = gt one-hot
__device__ __forceinline__ float4 load_src4(const float* __restrict__ net,
                                            const int* __restrict__ tgt,
                                            int i, long p) {
    if (i < 4) {
        int b = i >> 1, c = (i & 1) + 1;
        return *(const float4*)(net + (long)(b * 3 + c) * V_ + p);
    } else {
        int j = i - 4;
        int b = j >> 1, c = (j & 1) + 1;
        int4 t = *(const int4*)(tgt + (long)b * V_ + p);
        float4 o;
        int tx = t.x < 0 ? 0 : (t.x > 2 ? 2 : t.x);
        int ty = t.y < 0 ? 0 : (t.y > 2 ? 2 : t.y);
        int tz = t.z < 0 ? 0 : (t.z > 2 ? 2 : t.z);
        int tw = t.w < 0 ? 0 : (t.w > 2 ? 2 : t.w);
        o.x = (tx == c) ? 1.0f : 0.0f;
        o.y = (ty == c) ? 1.0f : 0.0f;
        o.z = (tz == c) ? 1.0f : 0.0f;
        o.w = (tw == c) ? 1.0f : 0.0f;
        return o;
    }
}

// Two skeleton iterations fused, thread-per-column z-march.
// VAR 0 (A): IN = src. Writes e2 volume + skel (after iters 0,1).
// VAR 1 (B): IN = e2. e3,e4 never leave the block; final skel in-register;
//            reduces fin vs partner into per-block partials. No volume writes.
//
// Barrier schedule (2 per step): W0,W1 | B1 | W2 | B2 | W3.
// Hazards: Pb RAW (W0(s)->W1(s+1)) covered by B1(s)/B2(s); Pb WAR
// (W1(s-1) last read of plane s-2 vs W0(s) overwrite) covered by B1(s-1).
// E1b RAW (W1(s-1)->W2(s)) via B1(s); E1b WAR (W2(s-1)->W1(s)) via B2(s-1).
// E2b RAW (W2->W3 same step) via B2; E2b WAR (W3(s-1)->W2(s)) via B1(s).
template <int VAR>
__global__ __launch_bounds__(NT, 7) void fused_pair(
    const float* __restrict__ net, const int* __restrict__ tgt, int i0,
    const float* __restrict__ e_in, float* __restrict__ e_out,
    float* __restrict__ skel, float* __restrict__ partials) {

    __shared__ float4 Pb[2][R_ * LROW];
    __shared__ float4 E1b[2][R_ * LROW];
    __shared__ float4 E2b[R_ * LROW];
    __shared__ float smr[NT / 64][2];

    const int j = blockIdx.y, i = i0 + j;
    const int bx = blockIdx.x;
    const int y0 = (bx % NYT) * TY;
    const int z0 = (bx / NYT) * ZC;
    const int tid = threadIdx.x;
    const int r  = tid / COLS;         // 0..15
    const int x4 = tid - r * COLS;     // 0..39
    const int y  = y0 - 3 + r;
    const bool yok  = (y >= 0 && y < H_);
    const bool ymok = (y - 1 >= 0 && y - 1 < H_);
    const bool ypok = (y + 1 >= 0 && y + 1 < H_);
    const int rm = (r > 0) ? r - 1 : 0;
    const int rp = (r < R_ - 1) ? r + 1 : R_ - 1;
    const int xm = (x4 > 0) ? x4 - 1 : 0;
    const int xp = (x4 < COLS - 1) ? x4 + 1 : COLS - 1;
    const bool fxm = (x4 > 0), fxp = (x4 < COLS - 1);
    const bool rout = (r >= 3 && r < 3 + TY);
    const long colbase = (long)(yok ? y : 0) * W_ + x4 * 4;

    const float* ein_v = (VAR == 1) ? e_in + (long)j * V_ : nullptr;
    float* eout_v = (VAR == 0) ? e_out + (long)j * V_ : nullptr;
    float* skel_v = skel + (long)j * V_;
    const int ipart = (i < 4) ? (i + 4) : (i - 4);

    const float4 INF4  = make_float4( INFINITY,  INFINITY,  INFINITY,  INFINITY);
    const float4 NINF4 = make_float4(-INFINITY, -INFINITY, -INFINITY, -INFINITY);

    // register rings (per-thread column)
    float4 a0 = INF4, a1 = INF4, a2 = INF4;           // P(s-3), P(s-2), P(s-1)
    float4 e11 = NINF4, e12 = NINF4;                  // e1(s-3), e1(s-2)
    float4 x1a = NINF4, x1b = NINF4;                  // xym1(s-4), xym1(s-3)
    float4 x2a = NINF4, x2b = NINF4;                  // xym2(s-4), xym2(s-3)
    float4 psk = make_float4(0,0,0,0), ppr = make_float4(0,0,0,0);
    float acc0 = 0.f, acc1 = 0.f;

    for (int s = z0 - 3; s <= z0 + ZC + 2; ++s) {
        // ---- W0: load input plane s; prefetch skel/partner for z=s-3 (VAR1)
        float4 anew;
        {
            const bool zok = (s >= 0 && s < D_);
            float4 v = INF4;
            if (zok && yok) {
                long p = (long)s * HW_ + colbase;
                v = (VAR == 0) ? load_src4(net, tgt, i, p)
                               : *(const float4*)(ein_v + p);
            }
            Pb[s & 1][r * LROW + x4] = v;
            anew = v;
            if (VAR == 1) {
                int z3 = s - 3;
                if (z3 >= z0 && z3 < z0 + ZC && rout) {
                    long p = (long)z3 * HW_ + colbase;
                    psk = *(const float4*)(skel_v + p);
                    ppr = load_src4(net, tgt, ipart, p);
                }
            }
        }

        // ---- W1: e1(s-1) = 7-pt cross erode of IN (reads Pb[(s-1)&1] only)
        float4 fe1;
        {
            const int z1 = s - 1;
            const bool z1ok = (z1 >= 0 && z1 < D_);
            const float4* Pp = Pb[z1 & 1];
            float4 up = Pp[rm * LROW + x4];
            float4 dn = Pp[rp * LROW + x4];
            float lf = Pp[r * LROW + xm].w;
            float rt = Pp[r * LROW + xp].x;
            if (!ymok) up = INF4;
            if (!ypok) dn = INF4;
            if (!fxm) lf = INFINITY;
            if (!fxp) rt = INFINITY;
            float4 e = f4min(f4min(min3x(lf, a2, rt), f4min(up, dn)), f4min(a1, anew));
            if (!z1ok || !yok) e = NINF4;
            fe1 = e;
            E1b[z1 & 1][r * LROW + x4] = e;
        }
        __syncthreads();   // B1

        // ---- W2: e2(s-2) (cross erode of e1) + xym1(s-2) (3x3 xy-max of e1)
        float4 fe2, f1;
        {
            const int z2 = s - 2;
            const bool z2ok = (z2 >= 0 && z2 < D_);
            const float4* Ep = E1b[z2 & 1];
            float4 n00 = Ep[rm*LROW+xm], n01 = Ep[rm*LROW+x4], n02 = Ep[rm*LROW+xp];
            float4 n10 = Ep[r *LROW+xm],                        n12 = Ep[r *LROW+xp];
            float4 n20 = Ep[rp*LROW+xm], n21 = Ep[rp*LROW+x4], n22 = Ep[rp*LROW+xp];
            float4 c = e12;
            // erode cross (min identities = +INF)
            {
                float4 up = ymok ? n01 : INF4;
                float4 dn = ypok ? n21 : INF4;
                float lf = fxm ? n10.w : INFINITY;
                float rt = fxp ? n12.x : INFINITY;
                float4 zu = (z2 >= 1)     ? e11 : INF4;
                float4 zd = (z2 + 1 < D_) ? fe1 : INF4;
                float4 e = f4min(f4min(min3x(lf, c, rt), f4min(up, dn)), f4min(zu, zd));
                if (!z2ok || !yok) e = NINF4;
                fe2 = e;
            }
            // xym1 (max identities = -INF; y-pad rows already -INF in LDS)
            {
                float l0 = fxm ? n00.w : -INFINITY, r0 = fxp ? n02.x : -INFINITY;
                float l1 = fxm ? n10.w : -INFINITY, r1 = fxp ? n12.x : -INFINITY;
                float l2 = fxm ? n20.w : -INFINITY, r2 = fxp ? n22.x : -INFINITY;
                float4 m = f4max(f4max(max3x(l0, n01, r0), max3x(l1, c, r1)), max3x(l2, n21, r2));
                if (!z2ok) m = NINF4;
                f1 = m;
            }
            E2b[r * LROW + x4] = fe2;
            if (VAR == 0 && z2 >= z0 && z2 < z0 + ZC && rout) {
                *(float4*)(eout_v + (long)z2 * HW_ + colbase) = fe2;
            }
        }
        __syncthreads();   // B2

        // ---- W3: xym2(s-2) + output plane z = s-3
        float4 f2;
        {
            float4 m00 = E2b[rm*LROW+xm], m01 = E2b[rm*LROW+x4], m02 = E2b[rm*LROW+xp];
            float4 m10 = E2b[r *LROW+xm],                         m12 = E2b[r *LROW+xp];
            float4 m20 = E2b[rp*LROW+xm], m21 = E2b[rp*LROW+x4], m22 = E2b[rp*LROW+xp];
            float l0 = fxm ? m00.w : -INFINITY, r0 = fxp ? m02.x : -INFINITY;
            float l1 = fxm ? m10.w : -INFINITY, r1 = fxp ? m12.x : -INFINITY;
            float l2 = fxm ? m20.w : -INFINITY, r2 = fxp ? m22.x : -INFINITY;
            f2 = f4max(f4max(max3x(l0, m01, r0), max3x(l1, fe2, r1)), max3x(l2, m21, r2));
        }
        {
            const int z3 = s - 3;
            if (z3 >= z0 && z3 < z0 + ZC && rout) {
                float4 dil1 = f4max(f4max(x1a, x1b), f1);
                float4 dil2 = f4max(f4max(x2a, x2b), f2);
                float4 cin = a0, ce1 = e11;
                long p = (long)z3 * HW_ + colbase;
                if (VAR == 0) {
                    float4 s0 = relu4sub(cin, dil1);        // relu(src - dil(e1))
                    float4 d1 = relu4sub(ce1, dil2);        // relu(e1 - dil(e2))
                    *(float4*)(skel_v + p) = skel_upd(s0, d1);
                } else {
                    float4 d2 = relu4sub(cin, dil1);        // relu(e2 - dil(e3))
                    float4 sp = skel_upd(psk, d2);
                    float4 d3 = relu4sub(ce1, dil2);        // relu(e3 - dil(e4))
                    float4 fin = skel_upd(sp, d3);
                    acc0 += fin.x * ppr.x + fin.y * ppr.y + fin.z * ppr.z + fin.w * ppr.w;
                    acc1 += fin.x + fin.y + fin.z + fin.w;
                }
            }
        }
        // ring shifts
        a0 = a1; a1 = a2; a2 = anew;
        e11 = e12; e12 = fe1;
        x1a = x1b; x1b = f1;
        x2a = x2b; x2b = f2;
    }

    if (VAR == 1) {
        #pragma unroll
        for (int off = 32; off > 0; off >>= 1) {
            acc0 += __shfl_down(acc0, off);
            acc1 += __shfl_down(acc1, off);
        }
        int wid = tid >> 6, lane = tid & 63;
        __syncthreads();
        if (lane == 0) { smr[wid][0] = acc0; smr[wid][1] = acc1; }
        __syncthreads();
        if (tid == 0) {
            float t0 = 0.f, t1 = 0.f;
            #pragma unroll
            for (int w = 0; w < NT / 64; ++w) { t0 += smr[w][0]; t1 += smr[w][1]; }
            long base = ((long)i * NTB + bx) * 2;
            partials[base + 0] = t0;
            partials[base + 1] = t1;
        }
    }
}

// one block (128 threads) per volume: sum NTB=128 partial pairs in double
__global__ void reduce_partials_kernel(const float* __restrict__ partials,
                                       int i0,
                                       double* __restrict__ sums) {
    int i = i0 + blockIdx.x;
    int t = threadIdx.x;    // 128
    long base = ((long)i * NTB + t) * 2;
    double v0 = (double)partials[base + 0];
    double v1 = (double)partials[base + 1];
    #pragma unroll
    for (int off = 32; off > 0; off >>= 1) {
        v0 += __shfl_down(v0, off);
        v1 += __shfl_down(v1, off);
    }
    __shared__ double sm[2][2];
    int wid = t >> 6, lane = t & 63;
    if (lane == 0) { sm[wid][0] = v0; sm[wid][1] = v1; }
    __syncthreads();
    if (t == 0) {
        sums[2 * i + 0] = sm[0][0] + sm[1][0];
        sums[2 * i + 1] = sm[0][1] + sm[1][1];
    }
}

__global__ void finalize_kernel(const double* __restrict__ sums,
                                float* __restrict__ out) {
    if (threadIdx.x == 0 && blockIdx.x == 0) {
        double acc = 0.0;
        #pragma unroll
        for (int i = 0; i < 4; ++i) {
            double tprec = (sums[2 * i + 0] + SMOOTHF) / (sums[2 * i + 1] + SMOOTHF);
            double tsens = (sums[2 * (i + 4) + 0] + SMOOTHF) / (sums[2 * (i + 4) + 1] + SMOOTHF);
            double cl = (2.0 * tprec * tsens + SMOOTHF) / (tprec + tsens + SMOOTHF);
            acc += cl;
        }
        out[0] = (float)(1.0 - acc * 0.25);
    }
}

extern "C" void kernel_launch(void* const* d_in, const int* in_sizes, int n_in,
                              void* d_out, int out_size, void* d_ws, size_t ws_size,
                              hipStream_t stream) {
    const float* net = (const float*)d_in[0];
    const int* tgt = (const int*)d_in[1];
    float* out = (float*)d_out;

    char* ws = (char*)d_ws;
    double* sums = (double*)ws;                      // 16 doubles
    float* partials = (float*)(ws + 256);            // 8*NTB*2 floats
    size_t head = 256 + (size_t)8 * NTB * 2 * sizeof(float);
    head = (head + 255) & ~(size_t)255;
    float* base = (float*)(ws + head);

    size_t perVol = (size_t)2 * V_ * sizeof(float);  // SKEL + E2 per volume
    int G = 1;
    if (ws_size >= head + perVol * 8) G = 8;
    else if (ws_size >= head + perVol * 4) G = 4;
    else if (ws_size >= head + perVol * 2) G = 2;

    dim3 blk(NT);
    dim3 grd(NTB, G);

    for (int i0 = 0; i0 < 8; i0 += G) {
        float* SKEL = base;
        float* E2buf = base + (size_t)G * V_;

        // A: src -> e2 volume + skel (iterations 0,1)
        fused_pair<0><<<grd, blk, 0, stream>>>(net, tgt, i0, nullptr, E2buf, SKEL, nullptr);
        // B: e2 -> (e3,e4 in LDS/regs), final skel in-register, reduce
        fused_pair<1><<<grd, blk, 0, stream>>>(net, tgt, i0, E2buf, nullptr, SKEL, partials);

        reduce_partials_kernel<<<G, 128, 0, stream>>>(partials, i0, sums);
    }

    finalize_kernel<<<1, 64, 0, stream>>>(sums, out);
}

// Round 9
// 342.305 us; speedup vs baseline: 2.0291x; 2.0291x over previous
//
#include <hip/hip_runtime.h>
#include <math.h>

#define D_ 128
#define H_ 160
#define W_ 160
#define HW_ (H_ * W_)            // 25600
#define V_ (D_ * H_ * W_)        // 3,276,800
#define SMOOTHF 1e-5

#define R_ 16                    // rows covered per block (TY + 6 halo)
#define TY 10                    // output rows per block
#define ZC 16                    // z-planes produced per block
#define COLS 40                  // float4 columns (W_/4)
#define NT 640                   // R_ * COLS threads (10 waves)
#define LROW 41                  // padded row length in float4 (164 floats)
#define NYT 16                   // H_/TY
#define NZC 8                    // D_/ZC
#define NTB (NYT * NZC)          // 128 tiles per volume

__device__ __forceinline__ float max3f(float a, float b, float c) { return fmaxf(fmaxf(a, b), c); }
__device__ __forceinline__ float min3f(float a, float b, float c) { return fminf(fminf(a, b), c); }
__device__ __forceinline__ float4 f4min(float4 a, float4 b) {
    return make_float4(fminf(a.x,b.x), fminf(a.y,b.y), fminf(a.z,b.z), fminf(a.w,b.w));
}
__device__ __forceinline__ float4 f4max(float4 a, float4 b) {
    return make_float4(fmaxf(a.x,b.x), fmaxf(a.y,b.y), fmaxf(a.z,b.z), fmaxf(a.w,b.w));
}
// sliding 3-window min/max along x of (l | c | r)
__device__ __forceinline__ float4 min3x(float l, float4 c, float r) {
    return make_float4(min3f(l,c.x,c.y), min3f(c.x,c.y,c.z), min3f(c.y,c.z,c.w), min3f(c.z,c.w,r));
}
__device__ __forceinline__ float4 max3x(float l, float4 c, float r) {
    return make_float4(max3f(l,c.x,c.y), max3f(c.x,c.y,c.z), max3f(c.y,c.z,c.w), max3f(c.z,c.w,r));
}
__device__ __forceinline__ float4 relu4sub(float4 a, float4 b) {   // relu(a-b)
    return make_float4(fmaxf(a.x-b.x,0.f), fmaxf(a.y-b.y,0.f), fmaxf(a.z-b.z,0.f), fmaxf(a.w-b.w,0.f));
}
__device__ __forceinline__ float4 skel_upd(float4 s, float4 d) {   // s + relu(d - s*d)
    return make_float4(s.x + fmaxf(d.x - s.x*d.x, 0.f), s.y + fmaxf(d.y - s.y*d.y, 0.f),
                       s.z + fmaxf(d.z - s.z*d.z, 0.f), s.w + fmaxf(d.w - s.w*d.w, 0.f));
}

// vol i in 0..7: 0..3 = pred (b=i>>1, ch=(i&1)+1), 4..7 = gt one-hot
__device__ __forceinline__ float4 load_src4(const float* __restrict__ net,
                                            const int* __restrict__ tgt,
                                            int i, long p) {
    if (i < 4) {
        int b = i >> 1, c = (i & 1) + 1;
        return *(const float4*)(net + (long)(b * 3 + c) * V_ + p);
    } else {
        int j = i - 4;
        int b = j >> 1, c = (j & 1) + 1;
        int4 t = *(const int4*)(tgt + (long)b * V_ + p);
        float4 o;
        int tx = t.x < 0 ? 0 : (t.x > 2 ? 2 : t.x);
        int ty = t.y < 0 ? 0 : (t.y > 2 ? 2 : t.y);
        int tz = t.z < 0 ? 0 : (t.z > 2 ? 2 : t.z);
        int tw = t.w < 0 ? 0 : (t.w > 2 ? 2 : t.w);
        o.x = (tx == c) ? 1.0f : 0.0f;
        o.y = (ty == c) ? 1.0f : 0.0f;
        o.z = (tz == c) ? 1.0f : 0.0f;
        o.w = (tw == c) ? 1.0f : 0.0f;
        return o;
    }
}

// Two skeleton iterations fused, thread-per-column z-march.
// VAR 0 (A): IN = src. Writes e2 volume + skel (after iters 0,1).
// VAR 1 (B): IN = e2. e3,e4 never leave the block; final skel in-register;
//            reduces fin vs partner into per-block partials. No volume writes.
//
// Barrier schedule (2 per step): W0,W1 | B1 | W2 | B2 | W3.
// Hazards: Pb RAW (W0(s)->W1(s+1)) covered by B1(s)/B2(s); Pb WAR
// (W1(s-1) last read of plane s-2 vs W0(s) overwrite) covered by B1(s-1).
// E1b RAW (W1(s-1)->W2(s)) via B1(s); E1b WAR (W2(s-1)->W1(s)) via B2(s-1).
// E2b RAW (W2->W3 same step) via B2; E2b WAR (W3(s-1)->W2(s)) via B1(s).
//
// NOTE __launch_bounds__ 2nd arg: empirically the compiler caps VGPR at
// ~256/min_waves. (NT,7) forced VGPR 48->36 and spilled the float4 register
// rings to scratch (+461 MB writes/dispatch, 377->694 us regression, R8).
// (NT,4) -> cap 64: no spill, and VGPR<=64 still allows full residency.
template <int VAR>
__global__ __launch_bounds__(NT, 4) void fused_pair(
    const float* __restrict__ net, const int* __restrict__ tgt, int i0,
    const float* __restrict__ e_in, float* __restrict__ e_out,
    float* __restrict__ skel, float* __restrict__ partials) {

    __shared__ float4 Pb[2][R_ * LROW];
    __shared__ float4 E1b[2][R_ * LROW];
    __shared__ float4 E2b[R_ * LROW];
    __shared__ float smr[NT / 64][2];

    const int j = blockIdx.y, i = i0 + j;
    const int bx = blockIdx.x;
    const int y0 = (bx % NYT) * TY;
    const int z0 = (bx / NYT) * ZC;
    const int tid = threadIdx.x;
    const int r  = tid / COLS;         // 0..15
    const int x4 = tid - r * COLS;     // 0..39
    const int y  = y0 - 3 + r;
    const bool yok  = (y >= 0 && y < H_);
    const bool ymok = (y - 1 >= 0 && y - 1 < H_);
    const bool ypok = (y + 1 >= 0 && y + 1 < H_);
    const int rm = (r > 0) ? r - 1 : 0;
    const int rp = (r < R_ - 1) ? r + 1 : R_ - 1;
    const int xm = (x4 > 0) ? x4 - 1 : 0;
    const int xp = (x4 < COLS - 1) ? x4 + 1 : COLS - 1;
    const bool fxm = (x4 > 0), fxp = (x4 < COLS - 1);
    const bool rout = (r >= 3 && r < 3 + TY);
    const long colbase = (long)(yok ? y : 0) * W_ + x4 * 4;

    const float* ein_v = (VAR == 1) ? e_in + (long)j * V_ : nullptr;
    float* eout_v = (VAR == 0) ? e_out + (long)j * V_ : nullptr;
    float* skel_v = skel + (long)j * V_;
    const int ipart = (i < 4) ? (i + 4) : (i - 4);

    const float4 INF4  = make_float4( INFINITY,  INFINITY,  INFINITY,  INFINITY);
    const float4 NINF4 = make_float4(-INFINITY, -INFINITY, -INFINITY, -INFINITY);

    // register rings (per-thread column)
    float4 a0 = INF4, a1 = INF4, a2 = INF4;           // P(s-3), P(s-2), P(s-1)
    float4 e11 = NINF4, e12 = NINF4;                  // e1(s-3), e1(s-2)
    float4 x1a = NINF4, x1b = NINF4;                  // xym1(s-4), xym1(s-3)
    float4 x2a = NINF4, x2b = NINF4;                  // xym2(s-4), xym2(s-3)
    float4 psk = make_float4(0,0,0,0), ppr = make_float4(0,0,0,0);
    float acc0 = 0.f, acc1 = 0.f;

    for (int s = z0 - 3; s <= z0 + ZC + 2; ++s) {
        // ---- W0: load input plane s; prefetch skel/partner for z=s-3 (VAR1)
        float4 anew;
        {
            const bool zok = (s >= 0 && s < D_);
            float4 v = INF4;
            if (zok && yok) {
                long p = (long)s * HW_ + colbase;
                v = (VAR == 0) ? load_src4(net, tgt, i, p)
                               : *(const float4*)(ein_v + p);
            }
            Pb[s & 1][r * LROW + x4] = v;
            anew = v;
            if (VAR == 1) {
                int z3 = s - 3;
                if (z3 >= z0 && z3 < z0 + ZC && rout) {
                    long p = (long)z3 * HW_ + colbase;
                    psk = *(const float4*)(skel_v + p);
                    ppr = load_src4(net, tgt, ipart, p);
                }
            }
        }

        // ---- W1: e1(s-1) = 7-pt cross erode of IN (reads Pb[(s-1)&1] only)
        float4 fe1;
        {
            const int z1 = s - 1;
            const bool z1ok = (z1 >= 0 && z1 < D_);
            const float4* Pp = Pb[z1 & 1];
            float4 up = Pp[rm * LROW + x4];
            float4 dn = Pp[rp * LROW + x4];
            float lf = Pp[r * LROW + xm].w;
            float rt = Pp[r * LROW + xp].x;
            if (!ymok) up = INF4;
            if (!ypok) dn = INF4;
            if (!fxm) lf = INFINITY;
            if (!fxp) rt = INFINITY;
            float4 e = f4min(f4min(min3x(lf, a2, rt), f4min(up, dn)), f4min(a1, anew));
            if (!z1ok || !yok) e = NINF4;
            fe1 = e;
            E1b[z1 & 1][r * LROW + x4] = e;
        }
        __syncthreads();   // B1

        // ---- W2: e2(s-2) (cross erode of e1) + xym1(s-2) (3x3 xy-max of e1)
        float4 fe2, f1;
        {
            const int z2 = s - 2;
            const bool z2ok = (z2 >= 0 && z2 < D_);
            const float4* Ep = E1b[z2 & 1];
            float4 n00 = Ep[rm*LROW+xm], n01 = Ep[rm*LROW+x4], n02 = Ep[rm*LROW+xp];
            float4 n10 = Ep[r *LROW+xm],                        n12 = Ep[r *LROW+xp];
            float4 n20 = Ep[rp*LROW+xm], n21 = Ep[rp*LROW+x4], n22 = Ep[rp*LROW+xp];
            float4 c = e12;
            // erode cross (min identities = +INF)
            {
                float4 up = ymok ? n01 : INF4;
                float4 dn = ypok ? n21 : INF4;
                float lf = fxm ? n10.w : INFINITY;
                float rt = fxp ? n12.x : INFINITY;
                float4 zu = (z2 >= 1)     ? e11 : INF4;
                float4 zd = (z2 + 1 < D_) ? fe1 : INF4;
                float4 e = f4min(f4min(min3x(lf, c, rt), f4min(up, dn)), f4min(zu, zd));
                if (!z2ok || !yok) e = NINF4;
                fe2 = e;
            }
            // xym1 (max identities = -INF; y-pad rows already -INF in LDS)
            {
                float l0 = fxm ? n00.w : -INFINITY, r0 = fxp ? n02.x : -INFINITY;
                float l1 = fxm ? n10.w : -INFINITY, r1 = fxp ? n12.x : -INFINITY;
                float l2 = fxm ? n20.w : -INFINITY, r2 = fxp ? n22.x : -INFINITY;
                float4 m = f4max(f4max(max3x(l0, n01, r0), max3x(l1, c, r1)), max3x(l2, n21, r2));
                if (!z2ok) m = NINF4;
                f1 = m;
            }
            E2b[r * LROW + x4] = fe2;
            if (VAR == 0 && z2 >= z0 && z2 < z0 + ZC && rout) {
                *(float4*)(eout_v + (long)z2 * HW_ + colbase) = fe2;
            }
        }
        __syncthreads();   // B2

        // ---- W3: xym2(s-2) + output plane z = s-3
        float4 f2;
        {
            float4 m00 = E2b[rm*LROW+xm], m01 = E2b[rm*LROW+x4], m02 = E2b[rm*LROW+xp];
            float4 m10 = E2b[r *LROW+xm],                         m12 = E2b[r *LROW+xp];
            float4 m20 = E2b[rp*LROW+xm], m21 = E2b[rp*LROW+x4], m22 = E2b[rp*LROW+xp];
            float l0 = fxm ? m00.w : -INFINITY, r0 = fxp ? m02.x : -INFINITY;
            float l1 = fxm ? m10.w : -INFINITY, r1 = fxp ? m12.x : -INFINITY;
            float l2 = fxm ? m20.w : -INFINITY, r2 = fxp ? m22.x : -INFINITY;
            f2 = f4max(f4max(max3x(l0, m01, r0), max3x(l1, fe2, r1)), max3x(l2, m21, r2));
        }
        {
            const int z3 = s - 3;
            if (z3 >= z0 && z3 < z0 + ZC && rout) {
                float4 dil1 = f4max(f4max(x1a, x1b), f1);
                float4 dil2 = f4max(f4max(x2a, x2b), f2);
                float4 cin = a0, ce1 = e11;
                long p = (long)z3 * HW_ + colbase;
                if (VAR == 0) {
                    float4 s0 = relu4sub(cin, dil1);        // relu(src - dil(e1))
                    float4 d1 = relu4sub(ce1, dil2);        // relu(e1 - dil(e2))
                    *(float4*)(skel_v + p) = skel_upd(s0, d1);
                } else {
                    float4 d2 = relu4sub(cin, dil1);        // relu(e2 - dil(e3))
                    float4 sp = skel_upd(psk, d2);
                    float4 d3 = relu4sub(ce1, dil2);        // relu(e3 - dil(e4))
                    float4 fin = skel_upd(sp, d3);
                    acc0 += fin.x * ppr.x + fin.y * ppr.y + fin.z * ppr.z + fin.w * ppr.w;
                    acc1 += fin.x + fin.y + fin.z + fin.w;
                }
            }
        }
        // ring shifts
        a0 = a1; a1 = a2; a2 = anew;
        e11 = e12; e12 = fe1;
        x1a = x1b; x1b = f1;
        x2a = x2b; x2b = f2;
    }

    if (VAR == 1) {
        #pragma unroll
        for (int off = 32; off > 0; off >>= 1) {
            acc0 += __shfl_down(acc0, off);
            acc1 += __shfl_down(acc1, off);
        }
        int wid = tid >> 6, lane = tid & 63;
        __syncthreads();
        if (lane == 0) { smr[wid][0] = acc0; smr[wid][1] = acc1; }
        __syncthreads();
        if (tid == 0) {
            float t0 = 0.f, t1 = 0.f;
            #pragma unroll
            for (int w = 0; w < NT / 64; ++w) { t0 += smr[w][0]; t1 += smr[w][1]; }
            long base = ((long)i * NTB + bx) * 2;
            partials[base + 0] = t0;
            partials[base + 1] = t1;
        }
    }
}

// one block (128 threads) per volume: sum NTB=128 partial pairs in double
__global__ void reduce_partials_kernel(const float* __restrict__ partials,
                                       int i0,
                                       double* __restrict__ sums) {
    int i = i0 + blockIdx.x;
    int t = threadIdx.x;    // 128
    long base = ((long)i * NTB + t) * 2;
    double v0 = (double)partials[base + 0];
    double v1 = (double)partials[base + 1];
    #pragma unroll
    for (int off = 32; off > 0; off >>= 1) {
        v0 += __shfl_down(v0, off);
        v1 += __shfl_down(v1, off);
    }
    __shared__ double sm[2][2];
    int wid = t >> 6, lane = t & 63;
    if (lane == 0) { sm[wid][0] = v0; sm[wid][1] = v1; }
    __syncthreads();
    if (t == 0) {
        sums[2 * i + 0] = sm[0][0] + sm[1][0];
        sums[2 * i + 1] = sm[0][1] + sm[1][1];
    }
}

__global__ void finalize_kernel(const double* __restrict__ sums,
                                float* __restrict__ out) {
    if (threadIdx.x == 0 && blockIdx.x == 0) {
        double acc = 0.0;
        #pragma unroll
        for (int i = 0; i < 4; ++i) {
            double tprec = (sums[2 * i + 0] + SMOOTHF) / (sums[2 * i + 1] + SMOOTHF);
            double tsens = (sums[2 * (i + 4) + 0] + SMOOTHF) / (sums[2 * (i + 4) + 1] + SMOOTHF);
            double cl = (2.0 * tprec * tsens + SMOOTHF) / (tprec + tsens + SMOOTHF);
            acc += cl;
        }
        out[0] = (float)(1.0 - acc * 0.25);
    }
}

extern "C" void kernel_launch(void* const* d_in, const int* in_sizes, int n_in,
                              void* d_out, int out_size, void* d_ws, size_t ws_size,
                              hipStream_t stream) {
    const float* net = (const float*)d_in[0];
    const int* tgt = (const int*)d_in[1];
    float* out = (float*)d_out;

    char* ws = (char*)d_ws;
    double* sums = (double*)ws;                      // 16 doubles
    float* partials = (float*)(ws + 256);            // 8*NTB*2 floats
    size_t head = 256 + (size_t)8 * NTB * 2 * sizeof(float);
    head = (head + 255) & ~(size_t)255;
    float* base = (float*)(ws + head);

    size_t perVol = (size_t)2 * V_ * sizeof(float);  // SKEL + E2 per volume
    int G = 1;
    if (ws_size >= head + perVol * 8) G = 8;
    else if (ws_size >= head + perVol * 4) G = 4;
    else if (ws_size >= head + perVol * 2) G = 2;

    dim3 blk(NT);
    dim3 grd(NTB, G);

    for (int i0 = 0; i0 < 8; i0 += G) {
        float* SKEL = base;
        float* E2buf = base + (size_t)G * V_;

        // A: src -> e2 volume + skel (iterations 0,1)
        fused_pair<0><<<grd, blk, 0, stream>>>(net, tgt, i0, nullptr, E2buf, SKEL, nullptr);
        // B: e2 -> (e3,e4 in LDS/regs), final skel in-register, reduce
        fused_pair<1><<<grd, blk, 0, stream>>>(net, tgt, i0, E2buf, nullptr, SKEL, partials);

        reduce_partials_kernel<<<G, 128, 0, stream>>>(partials, i0, sums);
    }

    finalize_kernel<<<1, 64, 0, stream>>>(sums, out);
}

// Round 10
// 338.426 us; speedup vs baseline: 2.0524x; 1.0115x over previous
//
#include <hip/hip_runtime.h>
#include <math.h>

#define D_ 128
#define H_ 160
#define W_ 160
#define HW_ (H_ * W_)            // 25600
#define V_ (D_ * H_ * W_)        // 3,276,800
#define SMOOTHF 1e-5

#define R_ 16                    // rows covered per block (TY + 6 halo)
#define TY 10                    // output rows per block
#define ZC 16                    // z-planes produced per block
#define COLS 40                  // float4 columns (W_/4)
#define NT 640                   // R_ * COLS threads (10 waves)
#define LROW 41                  // padded row length in float4 (164 floats)
#define NYT 16                   // H_/TY
#define NZC 8                    // D_/ZC
#define NTB (NYT * NZC)          // 128 tiles per volume

__device__ __forceinline__ float max3f(float a, float b, float c) { return fmaxf(fmaxf(a, b), c); }
__device__ __forceinline__ float min3f(float a, float b, float c) { return fminf(fminf(a, b), c); }
__device__ __forceinline__ float4 f4min(float4 a, float4 b) {
    return make_float4(fminf(a.x,b.x), fminf(a.y,b.y), fminf(a.z,b.z), fminf(a.w,b.w));
}
__device__ __forceinline__ float4 f4max(float4 a, float4 b) {
    return make_float4(fmaxf(a.x,b.x), fmaxf(a.y,b.y), fmaxf(a.z,b.z), fmaxf(a.w,b.w));
}
// sliding 3-window min/max along x of (l | c | r)
__device__ __forceinline__ float4 min3x(float l, float4 c, float r) {
    return make_float4(min3f(l,c.x,c.y), min3f(c.x,c.y,c.z), min3f(c.y,c.z,c.w), min3f(c.z,c.w,r));
}
__device__ __forceinline__ float4 max3x(float l, float4 c, float r) {
    return make_float4(max3f(l,c.x,c.y), max3f(c.x,c.y,c.z), max3f(c.y,c.z,c.w), max3f(c.z,c.w,r));
}
__device__ __forceinline__ float4 relu4sub(float4 a, float4 b) {   // relu(a-b)
    return make_float4(fmaxf(a.x-b.x,0.f), fmaxf(a.y-b.y,0.f), fmaxf(a.z-b.z,0.f), fmaxf(a.w-b.w,0.f));
}
__device__ __forceinline__ float4 skel_upd(float4 s, float4 d) {   // s + relu(d - s*d)
    return make_float4(s.x + fmaxf(d.x - s.x*d.x, 0.f), s.y + fmaxf(d.y - s.y*d.y, 0.f),
                       s.z + fmaxf(d.z - s.z*d.z, 0.f), s.w + fmaxf(d.w - s.w*d.w, 0.f));
}

// vol i in 0..7: 0..3 = pred (b=i>>1, ch=(i&1)+1), 4..7 = gt one-hot
__device__ __forceinline__ float4 load_src4(const float* __restrict__ net,
                                            const int* __restrict__ tgt,
                                            int i, long p) {
    if (i < 4) {
        int b = i >> 1, c = (i & 1) + 1;
        return *(const float4*)(net + (long)(b * 3 + c) * V_ + p);
    } else {
        int j = i - 4;
        int b = j >> 1, c = (j & 1) + 1;
        int4 t = *(const int4*)(tgt + (long)b * V_ + p);
        float4 o;
        int tx = t.x < 0 ? 0 : (t.x > 2 ? 2 : t.x);
        int ty = t.y < 0 ? 0 : (t.y > 2 ? 2 : t.y);
        int tz = t.z < 0 ? 0 : (t.z > 2 ? 2 : t.z);
        int tw = t.w < 0 ? 0 : (t.w > 2 ? 2 : t.w);
        o.x = (tx == c) ? 1.0f : 0.0f;
        o.y = (ty == c) ? 1.0f : 0.0f;
        o.z = (tz == c) ? 1.0f : 0.0f;
        o.w = (tw == c) ? 1.0f : 0.0f;
        return o;
    }
}

// Two skeleton iterations fused, thread-per-column z-march.
// VAR 0 (A): IN = src. Writes e2 volume + skel (after iters 0,1).
// VAR 1 (B): IN = e2. e3,e4 never leave the block; final skel in-register;
//            reduces fin vs partner into per-block partials. No volume writes.
//
// Barrier schedule (2 per step): W0,W1 | B1 | W2 | B2 | W3 (hazards verified R7/R9).
//
// LDS layout: float4 planes + dedicated edge-component arrays (X = .x, W = .w).
// The old `.w`/`.x` member reads had float-stride 4 between adjacent lanes ->
// 8/32 banks -> ~4x conflict (SQ_LDS_BANK_CONFLICT 22M, 75% of LDS cycles).
// Edge arrays give consecutive-lane float reads -> conflict-free.
//
// __launch_bounds__ note: (NT,7) caps VGPR at ~36 and spills the register
// rings to scratch (R8 regression). Keep (NT,4) -> cap 64.
template <int VAR>
__global__ __launch_bounds__(NT, 4) void fused_pair(
    const float* __restrict__ net, const int* __restrict__ tgt, int i0,
    const float* __restrict__ e_in, float* __restrict__ e_out,
    float* __restrict__ skel, float* __restrict__ partials) {

    __shared__ float4 Pb[2][R_ * LROW];
    __shared__ float  PbX[2][R_ * COLS];
    __shared__ float  PbW[2][R_ * COLS];
    __shared__ float4 E1b[2][R_ * LROW];
    __shared__ float  E1bX[2][R_ * COLS];
    __shared__ float  E1bW[2][R_ * COLS];
    __shared__ float4 E2b[R_ * LROW];
    __shared__ float  E2bX[R_ * COLS];
    __shared__ float  E2bW[R_ * COLS];
    __shared__ float smr[NT / 64][2];

    const int j = blockIdx.y, i = i0 + j;
    const int bx = blockIdx.x;
    const int y0 = (bx % NYT) * TY;
    const int z0 = (bx / NYT) * ZC;
    const int tid = threadIdx.x;
    const int r  = tid / COLS;         // 0..15
    const int x4 = tid - r * COLS;     // 0..39
    const int y  = y0 - 3 + r;
    const bool yok  = (y >= 0 && y < H_);
    const bool ymok = (y - 1 >= 0 && y - 1 < H_);
    const bool ypok = (y + 1 >= 0 && y + 1 < H_);
    const int rm = (r > 0) ? r - 1 : 0;
    const int rp = (r < R_ - 1) ? r + 1 : R_ - 1;
    const int xm = (x4 > 0) ? x4 - 1 : 0;
    const int xp = (x4 < COLS - 1) ? x4 + 1 : COLS - 1;
    const bool fxm = (x4 > 0), fxp = (x4 < COLS - 1);
    const bool rout = (r >= 3 && r < 3 + TY);
    const long colbase = (long)(yok ? y : 0) * W_ + x4 * 4;

    const float* ein_v = (VAR == 1) ? e_in + (long)j * V_ : nullptr;
    float* eout_v = (VAR == 0) ? e_out + (long)j * V_ : nullptr;
    float* skel_v = skel + (long)j * V_;
    const int ipart = (i < 4) ? (i + 4) : (i - 4);

    const float4 INF4  = make_float4( INFINITY,  INFINITY,  INFINITY,  INFINITY);
    const float4 NINF4 = make_float4(-INFINITY, -INFINITY, -INFINITY, -INFINITY);

    // register rings (per-thread column)
    float4 a0 = INF4, a1 = INF4, a2 = INF4;           // P(s-3), P(s-2), P(s-1)
    float4 e11 = NINF4, e12 = NINF4;                  // e1(s-3), e1(s-2)
    float4 x1a = NINF4, x1b = NINF4;                  // xym1(s-4), xym1(s-3)
    float4 x2a = NINF4, x2b = NINF4;                  // xym2(s-4), xym2(s-3)
    float4 psk = make_float4(0,0,0,0), ppr = make_float4(0,0,0,0);
    float acc0 = 0.f, acc1 = 0.f;

    for (int s = z0 - 3; s <= z0 + ZC + 2; ++s) {
        // ---- W0: load input plane s; prefetch skel/partner for z=s-3 (VAR1)
        float4 anew;
        {
            const bool zok = (s >= 0 && s < D_);
            float4 v = INF4;
            if (zok && yok) {
                long p = (long)s * HW_ + colbase;
                v = (VAR == 0) ? load_src4(net, tgt, i, p)
                               : *(const float4*)(ein_v + p);
            }
            Pb[s & 1][r * LROW + x4] = v;
            PbX[s & 1][r * COLS + x4] = v.x;
            PbW[s & 1][r * COLS + x4] = v.w;
            anew = v;
            if (VAR == 1) {
                int z3 = s - 3;
                if (z3 >= z0 && z3 < z0 + ZC && rout) {
                    long p = (long)z3 * HW_ + colbase;
                    psk = *(const float4*)(skel_v + p);
                    ppr = load_src4(net, tgt, ipart, p);
                }
            }
        }

        // ---- W1: e1(s-1) = 7-pt cross erode of IN (reads plane (s-1) only)
        float4 fe1;
        {
            const int z1 = s - 1;
            const bool z1ok = (z1 >= 0 && z1 < D_);
            const float4* Pp = Pb[z1 & 1];
            const float* PpX = PbX[z1 & 1];
            const float* PpW = PbW[z1 & 1];
            float4 up = Pp[rm * LROW + x4];
            float4 dn = Pp[rp * LROW + x4];
            float lf = PpW[r * COLS + xm];
            float rt = PpX[r * COLS + xp];
            if (!ymok) up = INF4;
            if (!ypok) dn = INF4;
            if (!fxm) lf = INFINITY;
            if (!fxp) rt = INFINITY;
            float4 e = f4min(f4min(min3x(lf, a2, rt), f4min(up, dn)), f4min(a1, anew));
            if (!z1ok || !yok) e = NINF4;
            fe1 = e;
            E1b[z1 & 1][r * LROW + x4] = e;
            E1bX[z1 & 1][r * COLS + x4] = e.x;
            E1bW[z1 & 1][r * COLS + x4] = e.w;
        }
        __syncthreads();   // B1

        // ---- W2: e2(s-2) (cross erode of e1) + xym1(s-2) (3x3 xy-max of e1)
        float4 fe2, f1;
        {
            const int z2 = s - 2;
            const bool z2ok = (z2 >= 0 && z2 < D_);
            const float4* Ep = E1b[z2 & 1];
            const float* EpX = E1bX[z2 & 1];
            const float* EpW = E1bW[z2 & 1];
            float4 n01 = Ep[rm * LROW + x4];
            float4 n21 = Ep[rp * LROW + x4];
            float4 c = e12;
            float l0 = fxm ? EpW[rm * COLS + xm] : -INFINITY;
            float r0 = fxp ? EpX[rm * COLS + xp] : -INFINITY;
            float l1 = fxm ? EpW[r  * COLS + xm] : -INFINITY;
            float r1 = fxp ? EpX[r  * COLS + xp] : -INFINITY;
            float l2 = fxm ? EpW[rp * COLS + xm] : -INFINITY;
            float r2 = fxp ? EpX[rp * COLS + xp] : -INFINITY;
            // erode cross (min identities = +INF)
            {
                float4 up = ymok ? n01 : INF4;
                float4 dn = ypok ? n21 : INF4;
                float lf = fxm ? l1 : INFINITY;   // same value, +INF when edge
                float rt = fxp ? r1 : INFINITY;
                float4 zu = (z2 >= 1)     ? e11 : INF4;
                float4 zd = (z2 + 1 < D_) ? fe1 : INF4;
                float4 e = f4min(f4min(min3x(lf, c, rt), f4min(up, dn)), f4min(zu, zd));
                if (!z2ok || !yok) e = NINF4;
                fe2 = e;
            }
            // xym1 (max identities = -INF; pad rows already -INF in LDS)
            {
                float4 m = f4max(f4max(max3x(l0, n01, r0), max3x(l1, c, r1)), max3x(l2, n21, r2));
                if (!z2ok) m = NINF4;
                f1 = m;
            }
            E2b[r * LROW + x4] = fe2;
            E2bX[r * COLS + x4] = fe2.x;
            E2bW[r * COLS + x4] = fe2.w;
            if (VAR == 0 && z2 >= z0 && z2 < z0 + ZC && rout) {
                *(float4*)(eout_v + (long)z2 * HW_ + colbase) = fe2;
            }
        }
        __syncthreads();   // B2

        // ---- W3: xym2(s-2) + output plane z = s-3
        float4 f2;
        {
            float4 m01 = E2b[rm * LROW + x4];
            float4 m21 = E2b[rp * LROW + x4];
            float l0 = fxm ? E2bW[rm * COLS + xm] : -INFINITY;
            float r0 = fxp ? E2bX[rm * COLS + xp] : -INFINITY;
            float l1 = fxm ? E2bW[r  * COLS + xm] : -INFINITY;
            float r1 = fxp ? E2bX[r  * COLS + xp] : -INFINITY;
            float l2 = fxm ? E2bW[rp * COLS + xm] : -INFINITY;
            float r2 = fxp ? E2bX[rp * COLS + xp] : -INFINITY;
            f2 = f4max(f4max(max3x(l0, m01, r0), max3x(l1, fe2, r1)), max3x(l2, m21, r2));
        }
        {
            const int z3 = s - 3;
            if (z3 >= z0 && z3 < z0 + ZC && rout) {
                float4 dil1 = f4max(f4max(x1a, x1b), f1);
                float4 dil2 = f4max(f4max(x2a, x2b), f2);
                float4 cin = a0, ce1 = e11;
                long p = (long)z3 * HW_ + colbase;
                if (VAR == 0) {
                    float4 s0 = relu4sub(cin, dil1);        // relu(src - dil(e1))
                    float4 d1 = relu4sub(ce1, dil2);        // relu(e1 - dil(e2))
                    *(float4*)(skel_v + p) = skel_upd(s0, d1);
                } else {
                    float4 d2 = relu4sub(cin, dil1);        // relu(e2 - dil(e3))
                    float4 sp = skel_upd(psk, d2);
                    float4 d3 = relu4sub(ce1, dil2);        // relu(e3 - dil(e4))
                    float4 fin = skel_upd(sp, d3);
                    acc0 += fin.x * ppr.x + fin.y * ppr.y + fin.z * ppr.z + fin.w * ppr.w;
                    acc1 += fin.x + fin.y + fin.z + fin.w;
                }
            }
        }
        // ring shifts
        a0 = a1; a1 = a2; a2 = anew;
        e11 = e12; e12 = fe1;
        x1a = x1b; x1b = f1;
        x2a = x2b; x2b = f2;
    }

    if (VAR == 1) {
        #pragma unroll
        for (int off = 32; off > 0; off >>= 1) {
            acc0 += __shfl_down(acc0, off);
            acc1 += __shfl_down(acc1, off);
        }
        int wid = tid >> 6, lane = tid & 63;
        __syncthreads();
        if (lane == 0) { smr[wid][0] = acc0; smr[wid][1] = acc1; }
        __syncthreads();
        if (tid == 0) {
            float t0 = 0.f, t1 = 0.f;
            #pragma unroll
            for (int w = 0; w < NT / 64; ++w) { t0 += smr[w][0]; t1 += smr[w][1]; }
            long base = ((long)i * NTB + bx) * 2;
            partials[base + 0] = t0;
            partials[base + 1] = t1;
        }
    }
}

// one block (128 threads) per volume: sum NTB=128 partial pairs in double
__global__ void reduce_partials_kernel(const float* __restrict__ partials,
                                       int i0,
                                       double* __restrict__ sums) {
    int i = i0 + blockIdx.x;
    int t = threadIdx.x;    // 128
    long base = ((long)i * NTB + t) * 2;
    double v0 = (double)partials[base + 0];
    double v1 = (double)partials[base + 1];
    #pragma unroll
    for (int off = 32; off > 0; off >>= 1) {
        v0 += __shfl_down(v0, off);
        v1 += __shfl_down(v1, off);
    }
    __shared__ double sm[2][2];
    int wid = t >> 6, lane = t & 63;
    if (lane == 0) { sm[wid][0] = v0; sm[wid][1] = v1; }
    __syncthreads();
    if (t == 0) {
        sums[2 * i + 0] = sm[0][0] + sm[1][0];
        sums[2 * i + 1] = sm[0][1] + sm[1][1];
    }
}

__global__ void finalize_kernel(const double* __restrict__ sums,
                                float* __restrict__ out) {
    if (threadIdx.x == 0 && blockIdx.x == 0) {
        double acc = 0.0;
        #pragma unroll
        for (int i = 0; i < 4; ++i) {
            double tprec = (sums[2 * i + 0] + SMOOTHF) / (sums[2 * i + 1] + SMOOTHF);
            double tsens = (sums[2 * (i + 4) + 0] + SMOOTHF) / (sums[2 * (i + 4) + 1] + SMOOTHF);
            double cl = (2.0 * tprec * tsens + SMOOTHF) / (tprec + tsens + SMOOTHF);
            acc += cl;
        }
        out[0] = (float)(1.0 - acc * 0.25);
    }
}

extern "C" void kernel_launch(void* const* d_in, const int* in_sizes, int n_in,
                              void* d_out, int out_size, void* d_ws, size_t ws_size,
                              hipStream_t stream) {
    const float* net = (const float*)d_in[0];
    const int* tgt = (const int*)d_in[1];
    float* out = (float*)d_out;

    char* ws = (char*)d_ws;
    double* sums = (double*)ws;                      // 16 doubles
    float* partials = (float*)(ws + 256);            // 8*NTB*2 floats
    size_t head = 256 + (size_t)8 * NTB * 2 * sizeof(float);
    head = (head + 255) & ~(size_t)255;
    float* base = (float*)(ws + head);

    size_t perVol = (size_t)2 * V_ * sizeof(float);  // SKEL + E2 per volume
    int G = 1;
    if (ws_size >= head + perVol * 8) G = 8;
    else if (ws_size >= head + perVol * 4) G = 4;
    else if (ws_size >= head + perVol * 2) G = 2;

    dim3 blk(NT);
    dim3 grd(NTB, G);

    for (int i0 = 0; i0 < 8; i0 += G) {
        float* SKEL = base;
        float* E2buf = base + (size_t)G * V_;

        // A: src -> e2 volume + skel (iterations 0,1)
        fused_pair<0><<<grd, blk, 0, stream>>>(net, tgt, i0, nullptr, E2buf, SKEL, nullptr);
        // B: e2 -> (e3,e4 in LDS/regs), final skel in-register, reduce
        fused_pair<1><<<grd, blk, 0, stream>>>(net, tgt, i0, E2buf, nullptr, SKEL, partials);

        reduce_partials_kernel<<<G, 128, 0, stream>>>(partials, i0, sums);
    }

    finalize_kernel<<<1, 64, 0, stream>>>(sums, out);
}